// Round 7
// baseline (365.075 us; speedup 1.0000x reference)
//
#include <hip/hip_runtime.h>
#include <math.h>

namespace {

constexpr int D    = 49;
constexpr int H    = 8;
constexpr int L    = 4;
constexpr int HID  = 25;
constexpr int NCLS = 10;
constexpr int XS   = 68;    // LDS X row stride (bf16 elems)
constexpr int WSM  = 4096;  // ushorts per padded 64x64 matrix in chunk-frag layout
constexpr float NEGBIG = -1e30f;  // finite mask: exp(NEGBIG - mx) == 0, no inf-inf

typedef __attribute__((ext_vector_type(4))) short short4v;
typedef __attribute__((ext_vector_type(8))) short short8v;
typedef __attribute__((ext_vector_type(4))) float float4v;
typedef __attribute__((ext_vector_type(4))) __bf16 bf16x4;

// One 16x16x32 bf16 MFMA; operands = concat of two 4-elem k-chunks.
// Consistent A/B chunk packing => correct contraction regardless of HW k-map.
__device__ __forceinline__ float4v mfma32(short4v alo, short4v ahi,
                                          short4v blo, short4v bhi, float4v c) {
  short8v a = __builtin_shufflevector(alo, ahi, 0, 1, 2, 3, 4, 5, 6, 7);
  short8v b = __builtin_shufflevector(blo, bhi, 0, 1, 2, 3, 4, 5, 6, 7);
  return __builtin_amdgcn_mfma_f32_16x16x32_bf16(a, b, c, 0, 0, 0);
}

__device__ __forceinline__ unsigned short f2bf(float x) {  // RNE bit-twiddle
  unsigned u = __float_as_uint(x);
  return (unsigned short)((u + 0x7FFFu + ((u >> 16) & 1u)) >> 16);
}

__device__ __forceinline__ short4v cvt4(float4v v) {  // 4xf32 -> 4xbf16 (compiler cvt)
  bf16x4 b = {(__bf16)v[0], (__bf16)v[1], (__bf16)v[2], (__bf16)v[3]};
  return __builtin_bit_cast(short4v, b);
}

__device__ __forceinline__ float4v splat4(float x) {
  float4v v; v[0] = x; v[1] = x; v[2] = x; v[3] = x; return v;
}

// chunk-frag (ktc, nt) of a prepped 64x64 matrix: semantic k = 16*ktc+4*g+j, col = 16*nt+c
__device__ __forceinline__ short4v wsld(const unsigned short* __restrict__ w,
                                        int ktc, int nt, int lane) {
  return *reinterpret_cast<const short4v*>(w + ((ktc * 4 + nt) * 64 + lane) * 4);
}

__device__ __forceinline__ float4v rowbias(const float* __restrict__ bp, int mt, int g) {
  float4v r;
  #pragma unroll
  for (int i = 0; i < 4; ++i) {
    const int e = 16 * mt + 4 * g + i;
    r[i] = (e < D) ? bp[e] : 0.0f;
  }
  return r;
}

// acc(cfrag of OUT^T) = W^T @ SRC + rowbias, K=32 MFMA over chunk pairs
__device__ __forceinline__ void mmT(const unsigned short* __restrict__ w,
                                    const short4v (&src)[4][4],
                                    const float* __restrict__ bp,
                                    int g, int lane, float4v (&acc)[4][4]) {
  #pragma unroll
  for (int mt = 0; mt < 4; ++mt) {
    const float4v rb = rowbias(bp, mt, g);
    #pragma unroll
    for (int nt = 0; nt < 4; ++nt) acc[mt][nt] = rb;
  }
  #pragma unroll
  for (int k2 = 0; k2 < 2; ++k2) {
    short4v alo[4], ahi[4];
    #pragma unroll
    for (int mt = 0; mt < 4; ++mt) {
      alo[mt] = wsld(w, 2 * k2,     mt, lane);
      ahi[mt] = wsld(w, 2 * k2 + 1, mt, lane);
    }
    #pragma unroll
    for (int nt = 0; nt < 4; ++nt)
      #pragma unroll
      for (int mt = 0; mt < 4; ++mt)
        acc[mt][nt] = mfma32(alo[mt], ahi[mt],
                             src[2 * k2][nt], src[2 * k2 + 1][nt], acc[mt][nt]);
  }
}

// Pre-shuffle one 49x49 f32 matrix into padded 64x64 bf16 chunk-frag layout.
__global__ void __launch_bounds__(256)
prep_weights(const float* __restrict__ Wq, const float* __restrict__ Wk,
             const float* __restrict__ Wv, const float* __restrict__ Wh,
             const float* __restrict__ Wout, const float* __restrict__ W1,
             const float* __restrict__ W2, unsigned short* __restrict__ ws) {
  const int m = blockIdx.x;  // 0..167
  const float* src;
  if (m < 32)       src = Wq   + (size_t)m * D * D;
  else if (m < 64)  src = Wk   + (size_t)(m - 32) * D * D;
  else if (m < 96)  src = Wv   + (size_t)(m - 64) * D * D;
  else if (m < 128) src = Wh   + (size_t)(m - 96) * D * D;
  else if (m < 160) src = Wout + (size_t)(m - 128) * D * D;
  else if (m < 164) src = W1   + (size_t)(m - 160) * D * D;
  else              src = W2   + (size_t)(m - 164) * D * D;

  const int t = threadIdx.x;
  const int ktc = t >> 6, lane = t & 63;
  const int gg = lane >> 4, cc = lane & 15;
  #pragma unroll
  for (int nt = 0; nt < 4; ++nt) {
    short4v v;
    #pragma unroll
    for (int j = 0; j < 4; ++j) {
      const int k = 16 * ktc + 4 * gg + j;
      const int n = 16 * nt + cc;
      const float f = (k < D && n < D) ? src[k * D + n] : 0.0f;
      v[j] = (short)f2bf(f);
    }
    *reinterpret_cast<short4v*>(ws + (size_t)m * WSM + ((ktc * 4 + nt) * 64 + lane) * 4) = v;
  }
}

__global__ void __launch_bounds__(64, 2)
encoder_kernel(const float* __restrict__ emb, const int* __restrict__ labels,
               const unsigned short* __restrict__ ws,
               const float* __restrict__ bq, const float* __restrict__ bk,
               const float* __restrict__ bv, const float* __restrict__ bh,
               const float* __restrict__ b1, const float* __restrict__ b2,
               const float* __restrict__ Wc1, const float* __restrict__ bc1,
               const float* __restrict__ Wc2, const float* __restrict__ bc2,
               float* __restrict__ ws_loss, float* __restrict__ ws_corr) {
  __shared__ unsigned short X[64 * XS];  // residual stream, [row][col] bf16
  __shared__ float CLS[128];

  const int b = blockIdx.x;
  const int lane = threadIdx.x;          // one wave per block
  const int g = lane >> 4, c = lane & 15;

  // ---- X <- embedding (zero-padded to 64x64) ----
  for (int idx = lane; idx < 64 * 64; idx += 64) {
    const int r = idx >> 6, cc = idx & 63;
    const float v = (r < D && cc < D) ? emb[(size_t)b * (D * D) + r * D + cc] : 0.0f;
    X[r * XS + cc] = f2bf(v);
  }
  __syncthreads();

  const float invSCALE = 1.0f / (7.0f + 1e-6f);

  short4v xf[4][4];    // xf[ktc][mt]: X[16mt+c][16ktc+4g..+3] (A-chunk of X)
  float4v xacc[4][4];  // layer output cfrag (kept for pooling)

  #pragma unroll 1
  for (int l = 0; l < L; ++l) {
    #pragma unroll
    for (int ktc = 0; ktc < 4; ++ktc)
      #pragma unroll
      for (int mt = 0; mt < 4; ++mt)
        xf[ktc][mt] = *reinterpret_cast<const short4v*>(
            &X[(16 * mt + c) * XS + 16 * ktc + 4 * g]);

    float4v od[4][4];  // od^T f32 accumulator across heads
    #pragma unroll
    for (int mt = 0; mt < 4; ++mt)
      #pragma unroll
      for (int nt = 0; nt < 4; ++nt) od[mt][nt] = splat4(0.0f);

    #pragma unroll 1
    for (int h = 0; h < H; ++h) {
      const int lh = l * H + h;
      const unsigned short* wq = ws + (size_t)(0   + lh) * WSM;
      const unsigned short* wk = ws + (size_t)(32  + lh) * WSM;
      const unsigned short* wv = ws + (size_t)(64  + lh) * WSM;
      const unsigned short* wh = ws + (size_t)(96  + lh) * WSM;
      const unsigned short* wo = ws + (size_t)(128 + lh) * WSM;

      // ---- Q^T, K^T (cfrag; rows = e dim = next contraction chunk) ----
      float4v qa[4][4], ka[4][4];
      mmT(wq, xf, bq + lh * D, g, lane, qa);
      mmT(wk, xf, bk + lh * D, g, lane, ka);
      short4v qf[4][4], kf[4][4];
      #pragma unroll
      for (int mt = 0; mt < 4; ++mt)
        #pragma unroll
        for (int nt = 0; nt < 4; ++nt) { qf[mt][nt] = cvt4(qa[mt][nt]); kf[mt][nt] = cvt4(ka[mt][nt]); }

      // ---- S^T = K @ Q^T ----
      float4v s[4][4];
      #pragma unroll
      for (int mt = 0; mt < 4; ++mt)
        #pragma unroll
        for (int nt = 0; nt < 4; ++nt) s[mt][nt] = splat4(0.0f);
      #pragma unroll
      for (int k2 = 0; k2 < 2; ++k2)
        #pragma unroll
        for (int nt = 0; nt < 4; ++nt)
          #pragma unroll
          for (int mt = 0; mt < 4; ++mt)
            s[mt][nt] = mfma32(kf[2 * k2][mt], kf[2 * k2 + 1][mt],
                               qf[2 * k2][nt], qf[2 * k2 + 1][nt], s[mt][nt]);

      // ---- scale, clip, mask pad keys j=16mt+4g+r>=49, softmax over j ----
      #pragma unroll
      for (int mt = 0; mt < 4; ++mt)
        #pragma unroll
        for (int nt = 0; nt < 4; ++nt)
          #pragma unroll
          for (int r = 0; r < 4; ++r) {
            float sv = s[mt][nt][r] * invSCALE;
            sv = fminf(fmaxf(sv, -30.0f), 30.0f);
            if (mt == 3) sv = (r == 0 && g == 0) ? sv : NEGBIG;
            s[mt][nt][r] = sv;
          }
      float inv_[4];
      #pragma unroll
      for (int nt = 0; nt < 4; ++nt) {
        float mx = s[0][nt][0];
        #pragma unroll
        for (int mt = 0; mt < 4; ++mt)
          #pragma unroll
          for (int r = 0; r < 4; ++r) mx = fmaxf(mx, s[mt][nt][r]);
        mx = fmaxf(mx, __shfl_xor(mx, 16));
        mx = fmaxf(mx, __shfl_xor(mx, 32));
        float dn = 0.0f;
        #pragma unroll
        for (int mt = 0; mt < 4; ++mt)
          #pragma unroll
          for (int r = 0; r < 4; ++r) {
            const float p = __expf(s[mt][nt][r] - mx);
            s[mt][nt][r] = p;
            dn += p;
          }
        dn += __shfl_xor(dn, 16);
        dn += __shfl_xor(dn, 32);
        inv_[nt] = 1.0f / fmaxf(dn, 1e-37f);
      }
      short4v pf[4][4];
      #pragma unroll
      for (int mt = 0; mt < 4; ++mt)
        #pragma unroll
        for (int nt = 0; nt < 4; ++nt) pf[mt][nt] = cvt4(s[mt][nt]);

      // ---- V = X @ Wv + bv (cfrag(V); rows = patch, cols = e) ----
      float4v va[4][4];
      #pragma unroll
      for (int nt = 0; nt < 4; ++nt) {
        const int e = 16 * nt + c;
        const float bvv = (e < D) ? bv[lh * D + e] : 0.0f;
        #pragma unroll
        for (int mt = 0; mt < 4; ++mt) va[mt][nt] = splat4(bvv);
      }
      #pragma unroll
      for (int k2 = 0; k2 < 2; ++k2) {
        short4v blo[4], bhi[4];
        #pragma unroll
        for (int nt = 0; nt < 4; ++nt) {
          blo[nt] = wsld(wv, 2 * k2,     nt, lane);
          bhi[nt] = wsld(wv, 2 * k2 + 1, nt, lane);
        }
        #pragma unroll
        for (int nt = 0; nt < 4; ++nt)
          #pragma unroll
          for (int mt = 0; mt < 4; ++mt)
            va[mt][nt] = mfma32(xf[2 * k2][mt], xf[2 * k2 + 1][mt],
                                blo[nt], bhi[nt], va[mt][nt]);
      }
      short4v vf[4][4];
      #pragma unroll
      for (int mt = 0; mt < 4; ++mt)
        #pragma unroll
        for (int nt = 0; nt < 4; ++nt) vf[mt][nt] = cvt4(va[mt][nt]);

      // ---- ctx^T = V^T @ P^T, then * inv_den per column ----
      float4v ca[4][4];
      #pragma unroll
      for (int mt = 0; mt < 4; ++mt)
        #pragma unroll
        for (int nt = 0; nt < 4; ++nt) ca[mt][nt] = splat4(0.0f);
      #pragma unroll
      for (int k2 = 0; k2 < 2; ++k2)
        #pragma unroll
        for (int nt = 0; nt < 4; ++nt)
          #pragma unroll
          for (int mt = 0; mt < 4; ++mt)
            ca[mt][nt] = mfma32(vf[2 * k2][mt], vf[2 * k2 + 1][mt],
                                pf[2 * k2][nt], pf[2 * k2 + 1][nt], ca[mt][nt]);
      short4v cf[4][4];
      #pragma unroll
      for (int mt = 0; mt < 4; ++mt)
        #pragma unroll
        for (int nt = 0; nt < 4; ++nt) cf[mt][nt] = cvt4(ca[mt][nt] * inv_[nt]);

      // ---- ho^T = Wh^T @ ctx^T + bh ----
      float4v ha[4][4];
      mmT(wh, cf, bh + lh * D, g, lane, ha);
      short4v hf[4][4];
      #pragma unroll
      for (int mt = 0; mt < 4; ++mt)
        #pragma unroll
        for (int nt = 0; nt < 4; ++nt) hf[mt][nt] = cvt4(ha[mt][nt]);

      // ---- od^T += Wout^T @ ho^T ----
      #pragma unroll
      for (int k2 = 0; k2 < 2; ++k2) {
        short4v alo[4], ahi[4];
        #pragma unroll
        for (int mt = 0; mt < 4; ++mt) {
          alo[mt] = wsld(wo, 2 * k2,     mt, lane);
          ahi[mt] = wsld(wo, 2 * k2 + 1, mt, lane);
        }
        #pragma unroll
        for (int nt = 0; nt < 4; ++nt)
          #pragma unroll
          for (int mt = 0; mt < 4; ++mt)
            od[mt][nt] = mfma32(alo[mt], ahi[mt],
                                hf[2 * k2][nt], hf[2 * k2 + 1][nt], od[mt][nt]);
      }
    }  // heads

    // ---- MLP: t^T = W1^T @ od^T + b1; x_new = t @ W2 + b2 ----
    short4v of[4][4];
    #pragma unroll
    for (int mt = 0; mt < 4; ++mt)
      #pragma unroll
      for (int nt = 0; nt < 4; ++nt) of[mt][nt] = cvt4(od[mt][nt]);
    float4v ta[4][4];
    mmT(ws + (size_t)(160 + l) * WSM, of, b1 + l * D, g, lane, ta);
    short4v tf[4][4];
    #pragma unroll
    for (int mt = 0; mt < 4; ++mt)
      #pragma unroll
      for (int nt = 0; nt < 4; ++nt) tf[mt][nt] = cvt4(ta[mt][nt]);

    const unsigned short* w2p = ws + (size_t)(164 + l) * WSM;
    #pragma unroll
    for (int nt = 0; nt < 4; ++nt) {
      const int e = 16 * nt + c;
      const float bvv = (e < D) ? b2[l * D + e] : 0.0f;
      #pragma unroll
      for (int mt = 0; mt < 4; ++mt) xacc[mt][nt] = splat4(bvv);
    }
    #pragma unroll
    for (int k2 = 0; k2 < 2; ++k2) {
      short4v blo[4], bhi[4];
      #pragma unroll
      for (int nt = 0; nt < 4; ++nt) {
        blo[nt] = wsld(w2p, 2 * k2,     nt, lane);
        bhi[nt] = wsld(w2p, 2 * k2 + 1, nt, lane);
      }
      #pragma unroll
      for (int nt = 0; nt < 4; ++nt)
        #pragma unroll
        for (int mt = 0; mt < 4; ++mt)
          xacc[mt][nt] = mfma32(tf[2 * k2][mt], tf[2 * k2 + 1][mt],
                                blo[nt], bhi[nt], xacc[mt][nt]);
    }

    if (l < L - 1) {
      __syncthreads();
      #pragma unroll
      for (int mt = 0; mt < 4; ++mt)
        #pragma unroll
        for (int nt = 0; nt < 4; ++nt)
          #pragma unroll
          for (int r = 0; r < 4; ++r)
            X[(16 * mt + 4 * g + r) * XS + 16 * nt + c] = f2bf(xacc[mt][nt][r]);
      __syncthreads();
    }
  }  // layers

  // ---- pooled = mean over rows<49 ----
  float ps[4];
  #pragma unroll
  for (int nt = 0; nt < 4; ++nt) {
    float sum = 0.0f;
    #pragma unroll
    for (int mt = 0; mt < 3; ++mt)
      #pragma unroll
      for (int r = 0; r < 4; ++r) sum += xacc[mt][nt][r];
    if (g == 0) sum += xacc[3][nt][0];  // row 48
    sum += __shfl_xor(sum, 16);
    sum += __shfl_xor(sum, 32);
    ps[nt] = sum * (1.0f / 49.0f);
  }
  if (lane < 16) {
    #pragma unroll
    for (int nt = 0; nt < 4; ++nt) CLS[16 * nt + lane] = ps[nt];
  }
  __syncthreads();

  if (lane < HID) {
    float acc = bc1[lane];
    #pragma unroll 1
    for (int d = 0; d < D; ++d) acc = fmaf(CLS[d], Wc1[d * HID + lane], acc);
    CLS[64 + lane] = acc;
  }
  __syncthreads();
  if (lane < NCLS) {
    float acc = bc2[lane];
    #pragma unroll 1
    for (int j = 0; j < HID; ++j) acc = fmaf(CLS[64 + j], Wc2[j * NCLS + lane], acc);
    CLS[96 + lane] = acc;
  }
  __syncthreads();
  if (lane == 0) {
    float mx = CLS[96];
    int am = 0;
    #pragma unroll 1
    for (int cc = 1; cc < NCLS; ++cc) {
      const float v = CLS[96 + cc];
      if (v > mx) { mx = v; am = cc; }  // strict '>' == first max (jnp.argmax)
    }
    float se = 0.0f;
    #pragma unroll 1
    for (int cc = 0; cc < NCLS; ++cc) se += expf(CLS[96 + cc] - mx);
    const float lse = mx + logf(se);
    const int lbl = labels[b];
    ws_loss[b] = lse - CLS[96 + lbl];
    ws_corr[b] = (am == lbl) ? 1.0f : 0.0f;
  }
}

__global__ void __launch_bounds__(256)
reduce_kernel(const float* __restrict__ wsl, const float* __restrict__ wsc,
              float* __restrict__ out, int n) {
  __shared__ float sl[256];
  __shared__ float sc[256];
  const int t = threadIdx.x;
  float a = 0.0f, cc = 0.0f;
  for (int idx = t; idx < n; idx += 256) { a += wsl[idx]; cc += wsc[idx]; }
  sl[t] = a; sc[t] = cc;
  __syncthreads();
  for (int s = 128; s > 0; s >>= 1) {
    if (t < s) { sl[t] += sl[t + s]; sc[t] += sc[t + s]; }
    __syncthreads();
  }
  if (t == 0) {
    out[0] = sl[0] / (float)n;
    out[1] = sc[0] / (float)n;
  }
}

}  // namespace

extern "C" void kernel_launch(void* const* d_in, const int* in_sizes, int n_in,
                              void* d_out, int out_size, void* d_ws, size_t ws_size,
                              hipStream_t stream) {
  const float* emb    = (const float*)d_in[0];
  const int*   labels = (const int*)d_in[1];
  const float* Wq   = (const float*)d_in[2];
  const float* bq   = (const float*)d_in[3];
  const float* Wk   = (const float*)d_in[4];
  const float* bk   = (const float*)d_in[5];
  const float* Wv   = (const float*)d_in[6];
  const float* bv   = (const float*)d_in[7];
  const float* Wh   = (const float*)d_in[8];
  const float* bh   = (const float*)d_in[9];
  const float* Wout = (const float*)d_in[10];
  const float* W1   = (const float*)d_in[11];
  const float* b1   = (const float*)d_in[12];
  const float* W2   = (const float*)d_in[13];
  const float* b2   = (const float*)d_in[14];
  const float* Wc1  = (const float*)d_in[15];
  const float* bc1  = (const float*)d_in[16];
  const float* Wc2  = (const float*)d_in[17];
  const float* bc2  = (const float*)d_in[18];

  const int B = in_sizes[1];  // 2048
  const size_t wBytes = (size_t)168 * WSM * sizeof(unsigned short);
  const size_t need = wBytes + (size_t)2 * B * sizeof(float);
  if (ws_size < need) return;

  unsigned short* wsb = (unsigned short*)d_ws;
  float* wsf = (float*)((char*)d_ws + wBytes);
  float* out = (float*)d_out;

  prep_weights<<<168, 256, 0, stream>>>(Wq, Wk, Wv, Wh, Wout, W1, W2, wsb);
  encoder_kernel<<<B, 64, 0, stream>>>(emb, labels, wsb, bq, bk, bv, bh,
                                       b1, b2, Wc1, bc1, Wc2, bc2,
                                       wsf, wsf + B);
  reduce_kernel<<<1, 256, 0, stream>>>(wsf, wsf + B, out, B);
}

// Round 8
// 268.681 us; speedup vs baseline: 1.3588x; 1.3588x over previous
//
#include <hip/hip_runtime.h>
#include <math.h>

namespace {

constexpr int D    = 49;
constexpr int H    = 8;
constexpr int L    = 4;
constexpr int HID  = 25;
constexpr int NCLS = 10;
constexpr int XS   = 68;    // LDS staging row stride (bf16 elems)
constexpr int WSM  = 4096;  // ushorts per padded 64x64 matrix in frag layout
constexpr float NEGBIG = -1e30f;

typedef __attribute__((ext_vector_type(4))) short short4v;
typedef __attribute__((ext_vector_type(8))) short short8v;
typedef __attribute__((ext_vector_type(4))) float float4v;
typedef __attribute__((ext_vector_type(8))) __bf16 bf16x8;

__device__ __forceinline__ float4v mfma32(short8v a, short8v b, float4v c) {
  return __builtin_amdgcn_mfma_f32_16x16x32_bf16(a, b, c, 0, 0, 0);
}

__device__ __forceinline__ unsigned short f2bf(float x) {  // RNE
  unsigned u = __float_as_uint(x);
  return (unsigned short)((u + 0x7FFFu + ((u >> 16) & 1u)) >> 16);
}

// two f32x4 accs -> one native short8v operand (4x v_cvt_pk_bf16_f32)
__device__ __forceinline__ short8v cvt8(float4v lo, float4v hi) {
  bf16x8 b = {(__bf16)lo[0], (__bf16)lo[1], (__bf16)lo[2], (__bf16)lo[3],
              (__bf16)hi[0], (__bf16)hi[1], (__bf16)hi[2], (__bf16)hi[3]};
  return __builtin_bit_cast(short8v, b);
}

__device__ __forceinline__ float4v splat4(float x) {
  float4v v; v[0] = x; v[1] = x; v[2] = x; v[3] = x; return v;
}

// full K=32 operand frag (t = chunk pair 0..1, nt = 16-col tile): one dwordx4
__device__ __forceinline__ short8v wsld8(const unsigned short* __restrict__ w,
                                         int t, int nt, int lane) {
  return *reinterpret_cast<const short8v*>(w + ((t * 4 + nt) * 64 + lane) * 8);
}

__device__ __forceinline__ float4v rowbias(const float* __restrict__ bp, int mt, int g) {
  float4v r;
  #pragma unroll
  for (int i = 0; i < 4; ++i) {
    const int e = 16 * mt + 4 * g + i;
    r[i] = (e < D) ? bp[e] : 0.0f;
  }
  return r;
}

// acc(cfrag of OUT^T) = W^T @ SRC + rowbias
__device__ __forceinline__ void mmT8(const unsigned short* __restrict__ w,
                                     const short8v (&src)[2][4],
                                     const float* __restrict__ bp,
                                     int g, int lane, float4v (&acc)[4][4]) {
  #pragma unroll
  for (int mt = 0; mt < 4; ++mt) {
    const float4v rb = rowbias(bp, mt, g);
    #pragma unroll
    for (int nt = 0; nt < 4; ++nt) acc[mt][nt] = rb;
  }
  #pragma unroll
  for (int t = 0; t < 2; ++t) {
    short8v a[4];
    #pragma unroll
    for (int mt = 0; mt < 4; ++mt) a[mt] = wsld8(w, t, mt, lane);
    #pragma unroll
    for (int nt = 0; nt < 4; ++nt)
      #pragma unroll
      for (int mt = 0; mt < 4; ++mt)
        acc[mt][nt] = mfma32(a[mt], src[t][nt], acc[mt][nt]);
  }
}

// Pre-shuffle 49x49 f32 -> padded 64x64 bf16, K=32-native frag layout:
// block (t,nt): 64 lanes x 8 shorts; lane(g,c) j: k=32t+4g+j (j<4) / 32t+16+4g+j-4,
// col n=16nt+c.
__global__ void __launch_bounds__(256)
prep_weights(const float* __restrict__ Wq, const float* __restrict__ Wk,
             const float* __restrict__ Wv, const float* __restrict__ Wh,
             const float* __restrict__ Wout, const float* __restrict__ W1,
             const float* __restrict__ W2, unsigned short* __restrict__ ws) {
  const int m = blockIdx.x;  // 0..167
  const float* src;
  if (m < 32)       src = Wq   + (size_t)m * D * D;
  else if (m < 64)  src = Wk   + (size_t)(m - 32) * D * D;
  else if (m < 96)  src = Wv   + (size_t)(m - 64) * D * D;
  else if (m < 128) src = Wh   + (size_t)(m - 96) * D * D;
  else if (m < 160) src = Wout + (size_t)(m - 128) * D * D;
  else if (m < 164) src = W1   + (size_t)(m - 160) * D * D;
  else              src = W2   + (size_t)(m - 164) * D * D;

  const int tid = threadIdx.x;
  const int lane = tid & 63;
  const int gg = (lane >> 4) & 3, cc = lane & 15;
  #pragma unroll
  for (int i = 0; i < 2; ++i) {
    const int p = ((tid >> 6) << 1) | i;  // 0..7
    const int tt = p >> 2, nt = p & 3;
    short8v v;
    #pragma unroll
    for (int j = 0; j < 8; ++j) {
      const int k = 32 * tt + ((j < 4) ? (4 * gg + j) : (16 + 4 * gg + j - 4));
      const int n = 16 * nt + cc;
      const float f = (k < D && n < D) ? src[k * D + n] : 0.0f;
      v[j] = (short)f2bf(f);
    }
    *reinterpret_cast<short8v*>(ws + (size_t)m * WSM + ((tt * 4 + nt) * 64 + lane) * 8) = v;
  }
}

__global__ void __launch_bounds__(64, 2)
encoder_kernel(const float* __restrict__ emb, const int* __restrict__ labels,
               const unsigned short* __restrict__ ws,
               const float* __restrict__ bq, const float* __restrict__ bk,
               const float* __restrict__ bv, const float* __restrict__ bh,
               const float* __restrict__ b1, const float* __restrict__ b2,
               const float* __restrict__ Wc1, const float* __restrict__ bc1,
               const float* __restrict__ Wc2, const float* __restrict__ bc2,
               float* __restrict__ ws_loss, float* __restrict__ ws_corr) {
  __shared__ unsigned short X[64 * XS];  // embedding staging only (layer 0)
  __shared__ float CLS[128];

  const int b = blockIdx.x;
  const int lane = threadIdx.x;          // one wave per block
  const int g = lane >> 4, c = lane & 15;

  // ---- stage embedding (zero-padded 64x64, row-major bf16) ----
  for (int idx = lane; idx < 64 * 64; idx += 64) {
    const int r = idx >> 6, cc = idx & 63;
    const float v = (r < D && cc < D) ? emb[(size_t)b * (D * D) + r * D + cc] : 0.0f;
    X[r * XS + cc] = f2bf(v);
  }
  __syncthreads();

  // xf8[t][nt] = operand frag of X (contraction over d): lane holds
  // X[patch=16nt+c][d=32t+4g+j, 32t+16+4g+j]
  short8v xf8[2][4];
  #pragma unroll
  for (int t = 0; t < 2; ++t)
    #pragma unroll
    for (int nt = 0; nt < 4; ++nt) {
      const int base = (16 * nt + c) * XS + 32 * t + 4 * g;
      short4v lo = *reinterpret_cast<const short4v*>(&X[base]);
      short4v hi = *reinterpret_cast<const short4v*>(&X[base + 16]);
      xf8[t][nt] = __builtin_shufflevector(lo, hi, 0, 1, 2, 3, 4, 5, 6, 7);
    }

  const float invSCALE = 1.0f / (7.0f + 1e-6f);
  float4v xacc[4][4];  // cfrag(x^T): rows d, cols patch

  #pragma unroll 1
  for (int l = 0; l < L; ++l) {
    float4v od[4][4];  // cfrag(od^T) f32 accumulator across heads
    #pragma unroll
    for (int mt = 0; mt < 4; ++mt)
      #pragma unroll
      for (int nt = 0; nt < 4; ++nt) od[mt][nt] = splat4(0.0f);

    #pragma unroll 1
    for (int h = 0; h < H; ++h) {
      const int lh = l * H + h;
      const unsigned short* wq = ws + (size_t)(0   + lh) * WSM;
      const unsigned short* wk = ws + (size_t)(32  + lh) * WSM;
      const unsigned short* wv = ws + (size_t)(64  + lh) * WSM;
      const unsigned short* wh = ws + (size_t)(96  + lh) * WSM;
      const unsigned short* wo = ws + (size_t)(128 + lh) * WSM;

      // ---- K^T then Q^T (sequential: free each f32 acc before the next) ----
      short8v kf8[2][4], qf8[2][4];
      {
        float4v ka[4][4];
        mmT8(wk, xf8, bk + lh * D, g, lane, ka);
        #pragma unroll
        for (int t = 0; t < 2; ++t)
          #pragma unroll
          for (int nt = 0; nt < 4; ++nt)
            kf8[t][nt] = cvt8(ka[2 * t][nt], ka[2 * t + 1][nt]);
      }
      {
        float4v qa[4][4];
        mmT8(wq, xf8, bq + lh * D, g, lane, qa);
        #pragma unroll
        for (int t = 0; t < 2; ++t)
          #pragma unroll
          for (int nt = 0; nt < 4; ++nt)
            qf8[t][nt] = cvt8(qa[2 * t][nt], qa[2 * t + 1][nt]);
      }

      // ---- S^T = K @ Q^T ----
      float4v s[4][4];
      #pragma unroll
      for (int mt = 0; mt < 4; ++mt)
        #pragma unroll
        for (int nt = 0; nt < 4; ++nt) s[mt][nt] = splat4(0.0f);
      #pragma unroll
      for (int t = 0; t < 2; ++t)
        #pragma unroll
        for (int nt = 0; nt < 4; ++nt)
          #pragma unroll
          for (int mt = 0; mt < 4; ++mt)
            s[mt][nt] = mfma32(kf8[t][mt], qf8[t][nt], s[mt][nt]);

      // ---- scale, clip, mask pad keys (j = 16mt+4g+r >= 49), softmax over j ----
      #pragma unroll
      for (int mt = 0; mt < 4; ++mt)
        #pragma unroll
        for (int nt = 0; nt < 4; ++nt)
          #pragma unroll
          for (int r = 0; r < 4; ++r) {
            float sv = s[mt][nt][r] * invSCALE;
            sv = fminf(fmaxf(sv, -30.0f), 30.0f);
            if (mt == 3) sv = (r == 0 && g == 0) ? sv : NEGBIG;
            s[mt][nt][r] = sv;
          }
      float inv_[4];
      #pragma unroll
      for (int nt = 0; nt < 4; ++nt) {
        float mx = s[0][nt][0];
        #pragma unroll
        for (int mt = 0; mt < 4; ++mt)
          #pragma unroll
          for (int r = 0; r < 4; ++r) mx = fmaxf(mx, s[mt][nt][r]);
        mx = fmaxf(mx, __shfl_xor(mx, 16));
        mx = fmaxf(mx, __shfl_xor(mx, 32));
        float dn = 0.0f;
        #pragma unroll
        for (int mt = 0; mt < 4; ++mt)
          #pragma unroll
          for (int r = 0; r < 4; ++r) {
            const float p = __expf(s[mt][nt][r] - mx);
            s[mt][nt][r] = p;
            dn += p;
          }
        dn += __shfl_xor(dn, 16);
        dn += __shfl_xor(dn, 32);
        inv_[nt] = 1.0f / fmaxf(dn, 1e-37f);
      }
      short8v pf8[2][4];  // P^T operand, chunks over key j
      #pragma unroll
      for (int t = 0; t < 2; ++t)
        #pragma unroll
        for (int nt = 0; nt < 4; ++nt)
          pf8[t][nt] = cvt8(s[2 * t][nt], s[2 * t + 1][nt]);

      // ---- V = X @ Wv + bv -> vf8 (operand of V^T, chunks over patch) ----
      short8v vf8[2][4];
      {
        float4v va[4][4];
        #pragma unroll
        for (int nt = 0; nt < 4; ++nt) {
          const int e = 16 * nt + c;
          const float bvv = (e < D) ? bv[lh * D + e] : 0.0f;
          #pragma unroll
          for (int mt = 0; mt < 4; ++mt) va[mt][nt] = splat4(bvv);
        }
        #pragma unroll
        for (int t = 0; t < 2; ++t) {
          short8v wvf[4];
          #pragma unroll
          for (int nt = 0; nt < 4; ++nt) wvf[nt] = wsld8(wv, t, nt, lane);
          #pragma unroll
          for (int nt = 0; nt < 4; ++nt)
            #pragma unroll
            for (int mt = 0; mt < 4; ++mt)
              va[mt][nt] = mfma32(xf8[t][mt], wvf[nt], va[mt][nt]);
        }
        #pragma unroll
        for (int t = 0; t < 2; ++t)
          #pragma unroll
          for (int nt = 0; nt < 4; ++nt)
            vf8[t][nt] = cvt8(va[2 * t][nt], va[2 * t + 1][nt]);
      }

      // ---- ctx^T = V^T @ P^T, * inv_den per query col -> cf8 (chunks over e) ----
      short8v cf8[2][4];
      {
        float4v ca[4][4];
        #pragma unroll
        for (int mt = 0; mt < 4; ++mt)
          #pragma unroll
          for (int nt = 0; nt < 4; ++nt) ca[mt][nt] = splat4(0.0f);
        #pragma unroll
        for (int t = 0; t < 2; ++t)
          #pragma unroll
          for (int nt = 0; nt < 4; ++nt)
            #pragma unroll
            for (int mt = 0; mt < 4; ++mt)
              ca[mt][nt] = mfma32(vf8[t][mt], pf8[t][nt], ca[mt][nt]);
        #pragma unroll
        for (int t = 0; t < 2; ++t)
          #pragma unroll
          for (int nt = 0; nt < 4; ++nt)
            cf8[t][nt] = cvt8(ca[2 * t][nt] * inv_[nt], ca[2 * t + 1][nt] * inv_[nt]);
      }

      // ---- ho^T = Wh^T @ ctx^T + bh -> hf8 (chunks over o) ----
      short8v hf8[2][4];
      {
        float4v ha[4][4];
        mmT8(wh, cf8, bh + lh * D, g, lane, ha);
        #pragma unroll
        for (int t = 0; t < 2; ++t)
          #pragma unroll
          for (int nt = 0; nt < 4; ++nt)
            hf8[t][nt] = cvt8(ha[2 * t][nt], ha[2 * t + 1][nt]);
      }

      // ---- od^T += Wout^T @ ho^T ----
      #pragma unroll
      for (int t = 0; t < 2; ++t) {
        short8v a[4];
        #pragma unroll
        for (int mt = 0; mt < 4; ++mt) a[mt] = wsld8(wo, t, mt, lane);
        #pragma unroll
        for (int nt = 0; nt < 4; ++nt)
          #pragma unroll
          for (int mt = 0; mt < 4; ++mt)
            od[mt][nt] = mfma32(a[mt], hf8[t][nt], od[mt][nt]);
      }
    }  // heads

    // ---- MLP: t^T = W1^T @ od^T + b1; x^T = W2^T @ t^T + b2 ----
    short8v of8[2][4];
    #pragma unroll
    for (int t = 0; t < 2; ++t)
      #pragma unroll
      for (int nt = 0; nt < 4; ++nt)
        of8[t][nt] = cvt8(od[2 * t][nt], od[2 * t + 1][nt]);
    short8v tf8[2][4];
    {
      float4v ta[4][4];
      mmT8(ws + (size_t)(160 + l) * WSM, of8, b1 + l * D, g, lane, ta);
      #pragma unroll
      for (int t = 0; t < 2; ++t)
        #pragma unroll
        for (int nt = 0; nt < 4; ++nt)
          tf8[t][nt] = cvt8(ta[2 * t][nt], ta[2 * t + 1][nt]);
    }
    mmT8(ws + (size_t)(164 + l) * WSM, tf8, b2 + l * D, g, lane, xacc);

    if (l < L - 1) {
      #pragma unroll
      for (int t = 0; t < 2; ++t)
        #pragma unroll
        for (int nt = 0; nt < 4; ++nt)
          xf8[t][nt] = cvt8(xacc[2 * t][nt], xacc[2 * t + 1][nt]);
    }
  }  // layers

  // ---- pooled[d] = mean over patches (cols of x^T); exclude pad cols ----
  #pragma unroll
  for (int mt = 0; mt < 4; ++mt) {
    float4v sum;
    #pragma unroll
    for (int r = 0; r < 4; ++r) {
      float sv = xacc[mt][0][r] + xacc[mt][1][r] + xacc[mt][2][r];
      if (c == 0) sv += xacc[mt][3][r];  // patch 48; 49..63 are pad
      sum[r] = sv;
    }
    #pragma unroll
    for (int r = 0; r < 4; ++r) {
      float sv = sum[r];
      sv += __shfl_xor(sv, 1);
      sv += __shfl_xor(sv, 2);
      sv += __shfl_xor(sv, 4);
      sv += __shfl_xor(sv, 8);
      if (c == 0) CLS[16 * mt + 4 * g + r] = sv * (1.0f / 49.0f);
    }
  }
  __syncthreads();

  // ---- classifier head (f32 scalar path) ----
  if (lane < HID) {
    float acc = bc1[lane];
    #pragma unroll 1
    for (int d = 0; d < D; ++d) acc = fmaf(CLS[d], Wc1[d * HID + lane], acc);
    CLS[64 + lane] = acc;
  }
  __syncthreads();
  if (lane < NCLS) {
    float acc = bc2[lane];
    #pragma unroll 1
    for (int j = 0; j < HID; ++j) acc = fmaf(CLS[64 + j], Wc2[j * NCLS + lane], acc);
    CLS[96 + lane] = acc;
  }
  __syncthreads();
  if (lane == 0) {
    float mx = CLS[96];
    int am = 0;
    #pragma unroll 1
    for (int cc = 1; cc < NCLS; ++cc) {
      const float v = CLS[96 + cc];
      if (v > mx) { mx = v; am = cc; }  // strict '>' == first max (jnp.argmax)
    }
    float se = 0.0f;
    #pragma unroll 1
    for (int cc = 0; cc < NCLS; ++cc) se += expf(CLS[96 + cc] - mx);
    const float lse = mx + logf(se);
    const int lbl = labels[b];
    ws_loss[b] = lse - CLS[96 + lbl];
    ws_corr[b] = (am == lbl) ? 1.0f : 0.0f;
  }
}

__global__ void __launch_bounds__(256)
reduce_kernel(const float* __restrict__ wsl, const float* __restrict__ wsc,
              float* __restrict__ out, int n) {
  __shared__ float sl[256];
  __shared__ float sc[256];
  const int t = threadIdx.x;
  float a = 0.0f, cc = 0.0f;
  for (int idx = t; idx < n; idx += 256) { a += wsl[idx]; cc += wsc[idx]; }
  sl[t] = a; sc[t] = cc;
  __syncthreads();
  for (int s = 128; s > 0; s >>= 1) {
    if (t < s) { sl[t] += sl[t + s]; sc[t] += sc[t + s]; }
    __syncthreads();
  }
  if (t == 0) {
    out[0] = sl[0] / (float)n;
    out[1] = sc[0] / (float)n;
  }
}

}  // namespace

extern "C" void kernel_launch(void* const* d_in, const int* in_sizes, int n_in,
                              void* d_out, int out_size, void* d_ws, size_t ws_size,
                              hipStream_t stream) {
  const float* emb    = (const float*)d_in[0];
  const int*   labels = (const int*)d_in[1];
  const float* Wq   = (const float*)d_in[2];
  const float* bq   = (const float*)d_in[3];
  const float* Wk   = (const float*)d_in[4];
  const float* bk   = (const float*)d_in[5];
  const float* Wv   = (const float*)d_in[6];
  const float* bv   = (const float*)d_in[7];
  const float* Wh   = (const float*)d_in[8];
  const float* bh   = (const float*)d_in[9];
  const float* Wout = (const float*)d_in[10];
  const float* W1   = (const float*)d_in[11];
  const float* b1   = (const float*)d_in[12];
  const float* W2   = (const float*)d_in[13];
  const float* b2   = (const float*)d_in[14];
  const float* Wc1  = (const float*)d_in[15];
  const float* bc1  = (const float*)d_in[16];
  const float* Wc2  = (const float*)d_in[17];
  const float* bc2  = (const float*)d_in[18];

  const int B = in_sizes[1];  // 2048
  const size_t wBytes = (size_t)168 * WSM * sizeof(unsigned short);
  const size_t need = wBytes + (size_t)2 * B * sizeof(float);
  if (ws_size < need) return;

  unsigned short* wsb = (unsigned short*)d_ws;
  float* wsf = (float*)((char*)d_ws + wBytes);
  float* out = (float*)d_out;

  prep_weights<<<168, 256, 0, stream>>>(Wq, Wk, Wv, Wh, Wout, W1, W2, wsb);
  encoder_kernel<<<B, 64, 0, stream>>>(emb, labels, wsb, bq, bk, bv, bh,
                                       b1, b2, Wc1, bc1, Wc2, bc2,
                                       wsf, wsf + B);
  reduce_kernel<<<1, 256, 0, stream>>>(wsf, wsf + B, out, B);
}